// Round 17
// baseline (523.143 us; speedup 1.0000x reference)
//
#include <hip/hip_runtime.h>
#include <hip/hip_bf16.h>
#include <stdint.h>

typedef int v4i __attribute__((ext_vector_type(4)));

#define GM 4096
#define GN 16384
#define GK 4096
#define BM 256
#define BN 128
#define BK 64         // i8 bytes per K-step
#define NT (GK / BK)  // 64 K-tiles

__device__ __forceinline__ void gload16(const void* g, void* l) {
  __builtin_amdgcn_global_load_lds(
      (const __attribute__((address_space(1))) void*)g,
      (__attribute__((address_space(3))) void*)l, 16, 0, 0);
}

// ---------------- per-row dynamic quantization -> fragment-ordered Xq2 ----------------
// Xq2[tm][kt][f 0..15][lane][16B]: lane l holds row tm*256 + f*16 + (l&15),
// k = kt*64 + (l>>4)*16 .. +16.
__global__ __launch_bounds__(256) void quant_rows(
    const float* __restrict__ x, int8_t* __restrict__ xq2,
    float* __restrict__ xs, int K) {
  const int row = blockIdx.x;
  const int t = threadIdx.x;
  const float4* src = (const float4*)(x + (size_t)row * K) + t * 4;
  float4 v[4];
  float m = 0.f;
#pragma unroll
  for (int i = 0; i < 4; ++i) {
    v[i] = src[i];
    m = fmaxf(m, fmaxf(fmaxf(fabsf(v[i].x), fabsf(v[i].y)),
                       fmaxf(fabsf(v[i].z), fabsf(v[i].w))));
  }
#pragma unroll
  for (int off = 1; off < 64; off <<= 1)
    m = fmaxf(m, __shfl_xor(m, off, 64));
  __shared__ float wmax[4];
  if ((t & 63) == 0) wmax[t >> 6] = m;
  __syncthreads();
  const float gm = fmaxf(fmaxf(wmax[0], wmax[1]), fmaxf(wmax[2], wmax[3]));
  const float scale = (gm + 1e-5f) / 127.0f;  // == ref x_scales
  if (t == 0) xs[row] = scale;
  unsigned packed[4];
#pragma unroll
  for (int i = 0; i < 4; ++i) {
    float fv[4] = {v[i].x, v[i].y, v[i].z, v[i].w};
    unsigned p = 0;
#pragma unroll
    for (int j = 0; j < 4; ++j) {
      int q = (int)rintf(fv[j] / scale);  // RNE, matches np.round
      q = max(-128, min(127, q));
      p |= (unsigned)(q & 0xff) << (8 * j);
    }
    packed[i] = p;
  }
  // thread t owns the 16B chunk at k = t*16: kt = t>>2, kg = t&3
  const int tm = row >> 8, f = (row >> 4) & 15, fr = row & 15;
  const int kt = t >> 2, kg = t & 3;
  int8_t* dst =
      xq2 + ((((size_t)(tm * 64 + kt) * 16 + f) * 64) + fr + 16 * kg) * 16;
  *(int4*)dst =
      make_int4((int)packed[0], (int)packed[1], (int)packed[2], (int)packed[3]);
}

// ------- W int32 [K][N] -> Wt2 int8, fragment order per 128-col panel -------
// Wt2[tn128][kt][f 0..7][lane][16B]: lane l holds col tn*128 + f*16 + (l&15),
// k = kt*64 + (l>>4)*16 .. +16.
__global__ __launch_bounds__(256) void transpose_pack(
    const int* __restrict__ W32, int8_t* __restrict__ Wt2, int K, int N) {
  __shared__ __align__(16) int8_t tile[64][80];
  const int t = threadIdx.x;
  const int n0 = blockIdx.x * 64;
  const int k0 = blockIdx.y * 64;
  const int ln = t & 63;
  const int wv = t >> 6;
#pragma unroll
  for (int it = 0; it < 16; ++it) {
    const int kk = wv * 16 + it;
    tile[ln][kk] = (int8_t)W32[(size_t)(k0 + kk) * N + n0 + ln];
  }
  __syncthreads();
  const int4 v = *(const int4*)&tile[wv * 16 + (ln & 15)][(ln >> 4) * 16];
  const int tn = n0 >> 7;
  const int kt = k0 >> 6;
  const int f = ((n0 >> 4) & 7) + wv;
  *(int4*)(Wt2 + (((size_t)(tn * 64 + kt) * 8 + f) * 64 + ln) * 16) = v;
}

// ---- int8 GEMM: 256x128 tile, 8 waves 4Mx2N (64x64/wave, 64-AGPR acc).      ----
// ---- A: 4-slot fragment-ordered LDS ring (halved read redundancy vs R13).   ----
// ---- B: direct global->VGPR 2-slot ring. Uniform vmcnt(6), never drained.   ----
__global__ __launch_bounds__(512, 2) void gemm_i8(
    const int8_t* __restrict__ Xq2, const int8_t* __restrict__ Wt2,
    const float* __restrict__ xs, const float* __restrict__ wsc,
    const float* __restrict__ bias, float* __restrict__ C) {
  __shared__ __align__(16) int8_t lA[4][16384];  // 64 KB: [slot][f][lane][16B]

  const int t = threadIdx.x;
  const int lane = t & 63;
  const int w = t >> 6;
  const int wr = w >> 1;  // 0..3 (M quarter: 64 rows)
  const int wc = w & 1;   // 0..1 (N half: 64 cols)
  const int fr = lane & 15;
  const int kg = lane >> 4;

  // bijective XCD swizzle: 2048 blocks = 8 XCD x (16 M x 16 N) rectangles
  const int bid = blockIdx.x;
  const int xcd = bid & 7;
  const int q = bid >> 3;
  const int tm = q & 15;
  const int tn = xcd * 16 + (q >> 4);
  const size_t rowA0 = (size_t)tm * BM;
  const size_t rowB0 = (size_t)tn * BN;

  // A tile (16 KB linear, fragment order); wave w stages 1KB chunks 2w, 2w+1.
  // global SOURCE per-lane (+lane*16); LDS dest wave-uniform (HW adds lane*16).
  const int8_t* aqB = Xq2 + (size_t)tm * 1048576 + w * 2048 + (size_t)lane * 16;
  const int dstO = w * 2048;

#define STAGE(KT, SLOT)                                           \
  {                                                               \
    const int8_t* p = aqB + (size_t)(KT)*16384;                   \
    gload16(p, &lA[(SLOT)][0] + dstO);                            \
    gload16(p + 1024, &lA[(SLOT)][0] + dstO + 1024);              \
  }

  // B: per-wave fragments f = wc*4 + nj; 8 KB panel per K-tile
  const int8_t* bq = Wt2 + (size_t)tn * 524288 + wc * 4096 + (size_t)lane * 16;

  v4i acc[4][4] = {};
  v4i areg[4], breg[2][4];  // B ring of 2: tile T lives in breg[T&1]

#define LD(dst, ptr)                                        \
  asm volatile("global_load_dwordx4 %0, %1, off"            \
               : "=v"(dst)                                  \
               : "v"(ptr)                                   \
               : "memory")

#define LOADB(KT, S)                                        \
  {                                                         \
    const int8_t* bp = bq + (size_t)(KT)*8192;              \
    LD(breg[S][0], bp);                                     \
    LD(breg[S][1], bp + 1024);                              \
    LD(breg[S][2], bp + 2048);                              \
    LD(breg[S][3], bp + 3072);                              \
  }

  // A fragment read: frag = wr*4 + mi, lane-linear -> conflict-free
#define RD_A(MI, SLOT)                                                     \
  areg[MI] = *(const v4i*)&lA[(SLOT)][(wr * 4 + (MI)) * 1024 + lane * 16];

#define SB __builtin_amdgcn_sched_barrier(0)

#define BODY(T, SLOT)                                                         \
  {                                                                           \
    /* top: B for tile T+1 into slot (T+1)&1 (WAR-safe: previous body's */    \
    /* MFMAs on that slot already issued; writeback is >100cy away) */        \
    LOADB(((T) + 1) & (NT - 1), ((SLOT) + 1) & 1);                            \
    SB;                                                                       \
    /* gate: stage(T)+B(T) landed; stage(T+1)+B(T+1)=6 newer may fly */       \
    asm volatile("s_waitcnt vmcnt(6)" ::: "memory");                          \
    __builtin_amdgcn_s_barrier(); /* CU-wide: tile T resident; slot free */   \
    STAGE(((T) + 2) & (NT - 1), ((SLOT) + 2) & 3);                            \
    SB;                                                                       \
    RD_A(0, SLOT); RD_A(1, SLOT); RD_A(2, SLOT); RD_A(3, SLOT);               \
    SB;                                                                       \
    asm volatile("s_waitcnt lgkmcnt(2)" ::: "memory"); /* A0,A1 ready */      \
    SB;                                                                       \
    __builtin_amdgcn_s_setprio(1);                                            \
    _Pragma("unroll") for (int mi = 0; mi < 2; ++mi)                          \
        _Pragma("unroll") for (int nj = 0; nj < 4; ++nj)                      \
            acc[mi][nj] = __builtin_amdgcn_mfma_i32_16x16x64_i8(              \
                areg[mi], breg[(SLOT)&1][nj], acc[mi][nj], 0, 0, 0);          \
    __builtin_amdgcn_s_setprio(0);                                            \
    asm volatile("s_waitcnt lgkmcnt(0)" ::: "memory"); /* A2,A3 ready */      \
    SB;                                                                       \
    __builtin_amdgcn_s_setprio(1);                                            \
    _Pragma("unroll") for (int mi = 2; mi < 4; ++mi)                          \
        _Pragma("unroll") for (int nj = 0; nj < 4; ++nj)                      \
            acc[mi][nj] = __builtin_amdgcn_mfma_i32_16x16x64_i8(              \
                areg[mi], breg[(SLOT)&1][nj], acc[mi][nj], 0, 0, 0);          \
    __builtin_amdgcn_s_setprio(0);                                            \
  }

  // prologue: B0 -> breg[0]; stage tiles 0,1.  Issue order (oldest first):
  // B0(4), S0(2), S1(2); BODY(0) adds B1(4) then gates vmcnt(6) -> B0,S0
  // landed with S1,B1 (=6) still flying.  Uniform forever after.
  LOADB(0, 0);
  STAGE(0, 0);
  STAGE(1, 1);

  for (int kt = 0; kt < NT; kt += 4) {
    BODY(kt, 0);
    BODY(kt + 1, 1);
    BODY(kt + 2, 2);
    BODY(kt + 3, 3);
  }
  // drain wrap-around prefetches so late writebacks can't clobber reused regs
  asm volatile("s_waitcnt vmcnt(0) lgkmcnt(0)" ::: "memory");
  SB;

  // epilogue: dequant + bias -> bf16-round -> f32 store
  // 16x16 C/D: col = lane&15, row = (lane>>4)*4 + reg
#pragma unroll
  for (int nj = 0; nj < 4; ++nj) {
    const int col_l = wc * 64 + nj * 16 + fr;
    const float wsv = wsc[rowB0 + col_l];
    const float bv = bias[rowB0 + col_l];
#pragma unroll
    for (int mi = 0; mi < 4; ++mi) {
#pragma unroll
      for (int r = 0; r < 4; ++r) {
        const size_t row = rowA0 + wr * 64 + mi * 16 + kg * 4 + r;
        const float f = (float)acc[mi][nj][r] * xs[row] * wsv + bv;
        C[row * GN + rowB0 + col_l] = __bfloat162float(__float2bfloat16(f));
      }
    }
  }
}

extern "C" void kernel_launch(void* const* d_in, const int* in_sizes, int n_in,
                              void* d_out, int out_size, void* d_ws, size_t ws_size,
                              hipStream_t stream) {
  const int M = GM, K = GK, N = GN;
  const float* x = (const float*)d_in[0];
  const int* W32 = (const int*)d_in[1];  // harness pushes integer inputs as int32
  const float* wsc = (const float*)d_in[2];
  const float* bias = (const float*)d_in[3];
  float* out = (float*)d_out;  // reference output dtype is float32 (bf16-rounded)

  // workspace layout: xs (16KB) | Xq2 (16MB packed) | Wt2 (64MB packed)
  float* xs = (float*)d_ws;
  int8_t* Xq2 = (int8_t*)d_ws + 16384;
  int8_t* Wt2 = (int8_t*)d_ws + 16384 + (size_t)M * K;

  transpose_pack<<<dim3(N / 64, K / 64), 256, 0, stream>>>(W32, Wt2, K, N);
  quant_rows<<<M, 256, 0, stream>>>(x, Xq2, xs, K);
  gemm_i8<<<dim3((M / BM) * (N / BN)), 512, 0, stream>>>(Xq2, Wt2, xs, wsc, bias,
                                                         out);
}

// Round 18
// 422.160 us; speedup vs baseline: 1.2392x; 1.2392x over previous
//
#include <hip/hip_runtime.h>
#include <hip/hip_bf16.h>
#include <stdint.h>

typedef int v4i __attribute__((ext_vector_type(4)));

#define GM 4096
#define GN 16384
#define GK 4096
#define BM 256
#define BN 256
#define BK 64         // i8 bytes per K-step
#define NT (GK / BK)  // 64 K-tiles

__device__ __forceinline__ void gload16(const void* g, void* l) {
  __builtin_amdgcn_global_load_lds(
      (const __attribute__((address_space(1))) void*)g,
      (__attribute__((address_space(3))) void*)l, 16, 0, 0);
}

// ---------------- per-row dynamic quantization -> fragment-ordered Xq2 ----------------
// Xq2[tm][kt][f 0..15][lane][16B]: lane l holds row tm*256 + f*16 + (l&15),
// k = kt*64 + (l>>4)*16 .. +16.   (verbatim R13)
__global__ __launch_bounds__(256) void quant_rows(
    const float* __restrict__ x, int8_t* __restrict__ xq2,
    float* __restrict__ xs, int K) {
  const int row = blockIdx.x;
  const int t = threadIdx.x;
  const float4* src = (const float4*)(x + (size_t)row * K) + t * 4;
  float4 v[4];
  float m = 0.f;
#pragma unroll
  for (int i = 0; i < 4; ++i) {
    v[i] = src[i];
    m = fmaxf(m, fmaxf(fmaxf(fabsf(v[i].x), fabsf(v[i].y)),
                       fmaxf(fabsf(v[i].z), fabsf(v[i].w))));
  }
#pragma unroll
  for (int off = 1; off < 64; off <<= 1)
    m = fmaxf(m, __shfl_xor(m, off, 64));
  __shared__ float wmax[4];
  if ((t & 63) == 0) wmax[t >> 6] = m;
  __syncthreads();
  const float gm = fmaxf(fmaxf(wmax[0], wmax[1]), fmaxf(wmax[2], wmax[3]));
  const float scale = (gm + 1e-5f) / 127.0f;  // == ref x_scales
  if (t == 0) xs[row] = scale;
  unsigned packed[4];
#pragma unroll
  for (int i = 0; i < 4; ++i) {
    float fv[4] = {v[i].x, v[i].y, v[i].z, v[i].w};
    unsigned p = 0;
#pragma unroll
    for (int j = 0; j < 4; ++j) {
      int q = (int)rintf(fv[j] / scale);  // RNE, matches np.round
      q = max(-128, min(127, q));
      p |= (unsigned)(q & 0xff) << (8 * j);
    }
    packed[i] = p;
  }
  const int tm = row >> 8, f = (row >> 4) & 15, fr = row & 15;
  const int kt = t >> 2, kg = t & 3;
  int8_t* dst =
      xq2 + ((((size_t)(tm * 64 + kt) * 16 + f) * 64) + fr + 16 * kg) * 16;
  *(int4*)dst =
      make_int4((int)packed[0], (int)packed[1], (int)packed[2], (int)packed[3]);
}

// ------- W int32 [K][N] -> Wt2 int8 fragment order, NO LDS -------
// Wt2[tn256][kt][f 0..15][slot][16B], slot = (n&15) + 16*((k>>4)&3).
// Thread owns a 4n x 16k block: 16 coalesced int4 reads (4 weights each),
// in-register byte transpose, 4 contiguous-by-construction dwordx4 stores.
__global__ __launch_bounds__(256) void transpose_pack(
    const int* __restrict__ W32, int8_t* __restrict__ Wt2, int K, int N) {
  const int t = threadIdx.x;
  const int tn = blockIdx.x;  // 256-col panel
  const int kt = blockIdx.y;  // 64-k tile
  const int nq = t & 63;      // n-quad index within panel (4n each)
  const int kg = t >> 6;      // 16-k group 0..3
  const int n0 = tn * 256 + nq * 4;
  const int kb = kt * 64 + kg * 16;

  // 16 coalesced loads: row kb+k, cols n0..n0+3 (int32 weights)
  v4i r[16];
#pragma unroll
  for (int k = 0; k < 16; ++k)
    r[k] = *(const v4i*)(W32 + (size_t)(kb + k) * N + n0);

  // transpose to o[i] = 16 k-bytes for col n0+i (byte jj of word j <- k=4j+jj)
  int o[4][4];
#pragma unroll
  for (int i = 0; i < 4; ++i)
#pragma unroll
    for (int j = 0; j < 4; ++j)
      o[i][j] = (r[4 * j + 0][i] & 0xff) | ((r[4 * j + 1][i] & 0xff) << 8) |
                ((r[4 * j + 2][i] & 0xff) << 16) | (r[4 * j + 3][i] << 24);

  // store: f = nq>>2; slots 4*(nq&3)+i + 16*kg are 16B-contiguous in i
  int8_t* base = Wt2 + (((size_t)(tn * 64 + kt) * 16 + (nq >> 2)) * 64 +
                        4 * (nq & 3) + 16 * kg) * 16;
#pragma unroll
  for (int i = 0; i < 4; ++i)
    *(v4i*)(base + i * 16) = *(v4i*)&o[i][0];
}

// ---- int8 GEMM (verbatim R13): A via fragment-ordered LDS ring, B direct ----
__global__ __launch_bounds__(512, 2) void gemm_i8(
    const int8_t* __restrict__ Xq2, const int8_t* __restrict__ Wt2,
    const float* __restrict__ xs, const float* __restrict__ wsc,
    const float* __restrict__ bias, float* __restrict__ C) {
  __shared__ __align__(16) int8_t lA[4][16384];  // 64 KB: [slot][f][lane][16B]

  const int t = threadIdx.x;
  const int lane = t & 63;
  const int w = t >> 6;
  const int wr = w >> 2;  // 0..1 (M half: 128 rows)
  const int wc = w & 3;   // 0..3 (N quarter: 64 cols)
  const int fr = lane & 15;
  const int kg = lane >> 4;

  // bijective XCD swizzle: 1024 blocks = 8 XCD x (16 M x 8 N) rectangles
  const int bid = blockIdx.x;
  const int xcd = bid & 7;
  const int q = bid >> 3;
  const int tm = q & 15;
  const int tn = xcd * 8 + (q >> 4);
  const size_t rowA0 = (size_t)tm * BM;
  const size_t rowB0 = (size_t)tn * BN;

  // A tile (16 KB linear, fragment order); wave w stages 1KB chunks 2w, 2w+1.
  const int8_t* aqB = Xq2 + (size_t)tm * 1048576 + w * 2048 + (size_t)lane * 16;
  const int dstO = w * 2048;

#define STAGE(KT, SLOT)                                           \
  {                                                               \
    const int8_t* p = aqB + (size_t)(KT)*16384;                   \
    gload16(p, &lA[(SLOT)][0] + dstO);                            \
    gload16(p + 1024, &lA[(SLOT)][0] + dstO + 1024);              \
  }

  // B fragment base for this wave: f = wc*4 + nj
  const int8_t* bq = Wt2 + (size_t)tn * 1048576 + wc * 4096 + (size_t)lane * 16;

  v4i acc[8][4] = {};
  v4i areg[8], breg[4][4];  // breg[slot][nj]

#define LD(dst, ptr)                                        \
  asm volatile("global_load_dwordx4 %0, %1, off"            \
               : "=v"(dst)                                  \
               : "v"(ptr)                                   \
               : "memory")

#define LOADB(KT, S)                                        \
  {                                                         \
    const int8_t* bp = bq + (size_t)(KT)*16384;             \
    LD(breg[S][0], bp);                                     \
    LD(breg[S][1], bp + 1024);                              \
    LD(breg[S][2], bp + 2048);                              \
    LD(breg[S][3], bp + 3072);                              \
  }

#define RD_A(MI, SLOT)                                                     \
  areg[MI] = *(const v4i*)&lA[(SLOT)][(wr * 8 + (MI)) * 1024 + lane * 16];

#define SB __builtin_amdgcn_sched_barrier(0)

#define BODY(T, SLOT)                                                         \
  {                                                                           \
    asm volatile("s_waitcnt vmcnt(12)" ::: "memory");                         \
    __builtin_amdgcn_s_barrier(); /* A(T) resident CU-wide; ring slot free */ \
    SB;                                                                       \
    STAGE(((T) + 3) & (NT - 1), ((SLOT) + 3) & 3);                            \
    LOADB(((T) + 3) & (NT - 1), ((SLOT) + 3) & 3);                            \
    SB;                                                                       \
    RD_A(0, SLOT); RD_A(1, SLOT); RD_A(2, SLOT); RD_A(3, SLOT);               \
    SB;                                                                       \
    RD_A(4, SLOT); RD_A(5, SLOT); RD_A(6, SLOT); RD_A(7, SLOT);               \
    SB;                                                                       \
    asm volatile("s_waitcnt lgkmcnt(4)" ::: "memory"); /* A0-3 ready */       \
    SB;                                                                       \
    __builtin_amdgcn_s_setprio(1);                                            \
    _Pragma("unroll") for (int mi = 0; mi < 4; ++mi)                          \
        _Pragma("unroll") for (int nj = 0; nj < 4; ++nj)                      \
            acc[mi][nj] = __builtin_amdgcn_mfma_i32_16x16x64_i8(              \
                areg[mi], breg[SLOT][nj], acc[mi][nj], 0, 0, 0);              \
    __builtin_amdgcn_s_setprio(0);                                            \
    asm volatile("s_waitcnt lgkmcnt(0)" ::: "memory"); /* A4-7 ready */       \
    SB;                                                                       \
    __builtin_amdgcn_s_setprio(1);                                            \
    _Pragma("unroll") for (int mi = 4; mi < 8; ++mi)                          \
        _Pragma("unroll") for (int nj = 0; nj < 4; ++nj)                      \
            acc[mi][nj] = __builtin_amdgcn_mfma_i32_16x16x64_i8(              \
                areg[mi], breg[SLOT][nj], acc[mi][nj], 0, 0, 0);              \
    __builtin_amdgcn_s_setprio(0);                                            \
  }

  // prologue: issue batches 0,1,2 (A-stage + B-loads each; 18 loads out)
  STAGE(0, 0);
  LOADB(0, 0);
  STAGE(1, 1);
  LOADB(1, 1);
  STAGE(2, 2);
  LOADB(2, 2);

  for (int kt = 0; kt < NT; kt += 4) {
    BODY(kt, 0);
    BODY(kt + 1, 1);
    BODY(kt + 2, 2);
    BODY(kt + 3, 3);
  }
  asm volatile("s_waitcnt vmcnt(0) lgkmcnt(0)" ::: "memory");
  SB;

  // epilogue: dequant + bias -> bf16-round -> f32 store
  // 16x16 C/D: col = lane&15, row = (lane>>4)*4 + reg
#pragma unroll
  for (int nj = 0; nj < 4; ++nj) {
    const int col_l = wc * 64 + nj * 16 + fr;
    const float wsv = wsc[rowB0 + col_l];
    const float bv = bias[rowB0 + col_l];
#pragma unroll
    for (int mi = 0; mi < 8; ++mi) {
#pragma unroll
      for (int r = 0; r < 4; ++r) {
        const size_t row = rowA0 + wr * 128 + mi * 16 + kg * 4 + r;
        const float f = (float)acc[mi][nj][r] * xs[row] * wsv + bv;
        C[row * GN + rowB0 + col_l] = __bfloat162float(__float2bfloat16(f));
      }
    }
  }
}

extern "C" void kernel_launch(void* const* d_in, const int* in_sizes, int n_in,
                              void* d_out, int out_size, void* d_ws, size_t ws_size,
                              hipStream_t stream) {
  const int M = GM, K = GK, N = GN;
  const float* x = (const float*)d_in[0];
  const int* W32 = (const int*)d_in[1];  // harness pushes integer inputs as int32
  const float* wsc = (const float*)d_in[2];
  const float* bias = (const float*)d_in[3];
  float* out = (float*)d_out;  // reference output dtype is float32 (bf16-rounded)

  // workspace layout: xs (16KB) | Xq2 (16MB packed) | Wt2 (64MB packed)
  float* xs = (float*)d_ws;
  int8_t* Xq2 = (int8_t*)d_ws + 16384;
  int8_t* Wt2 = (int8_t*)d_ws + 16384 + (size_t)M * K;

  transpose_pack<<<dim3(N / 256, K / 64), 256, 0, stream>>>(W32, Wt2, K, N);
  quant_rows<<<M, 256, 0, stream>>>(x, Xq2, xs, K);
  gemm_i8<<<dim3((M / BM) * (N / BN)), 512, 0, stream>>>(Xq2, Wt2, xs, wsc, bias,
                                                         out);
}

// Round 19
// 416.737 us; speedup vs baseline: 1.2553x; 1.0130x over previous
//
#include <hip/hip_runtime.h>
#include <hip/hip_bf16.h>
#include <stdint.h>

typedef int v4i __attribute__((ext_vector_type(4)));

#define GM 4096
#define GN 16384
#define GK 4096
#define BM 256
#define BN 256
#define BK 64         // i8 bytes per K-step
#define NT (GK / BK)  // 64 K-tiles

__device__ __forceinline__ void gload16(const void* g, void* l) {
  __builtin_amdgcn_global_load_lds(
      (const __attribute__((address_space(1))) void*)g,
      (__attribute__((address_space(3))) void*)l, 16, 0, 0);
}

// ---------------- per-row dynamic quantization -> fragment-ordered Xq2 ----------------
// Xq2[tm][kt][f 0..15][lane][16B]: lane l holds row tm*256 + f*16 + (l&15),
// k = kt*64 + (l>>4)*16 .. +16.
__global__ __launch_bounds__(256) void quant_rows(
    const float* __restrict__ x, int8_t* __restrict__ xq2,
    float* __restrict__ xs, int K) {
  const int row = blockIdx.x;
  const int t = threadIdx.x;
  const float4* src = (const float4*)(x + (size_t)row * K) + t * 4;
  float4 v[4];
  float m = 0.f;
#pragma unroll
  for (int i = 0; i < 4; ++i) {
    v[i] = src[i];
    m = fmaxf(m, fmaxf(fmaxf(fabsf(v[i].x), fabsf(v[i].y)),
                       fmaxf(fabsf(v[i].z), fabsf(v[i].w))));
  }
#pragma unroll
  for (int off = 1; off < 64; off <<= 1)
    m = fmaxf(m, __shfl_xor(m, off, 64));
  __shared__ float wmax[4];
  if ((t & 63) == 0) wmax[t >> 6] = m;
  __syncthreads();
  const float gm = fmaxf(fmaxf(wmax[0], wmax[1]), fmaxf(wmax[2], wmax[3]));
  const float scale = (gm + 1e-5f) / 127.0f;  // == ref x_scales
  if (t == 0) xs[row] = scale;
  unsigned packed[4];
#pragma unroll
  for (int i = 0; i < 4; ++i) {
    float fv[4] = {v[i].x, v[i].y, v[i].z, v[i].w};
    unsigned p = 0;
#pragma unroll
    for (int j = 0; j < 4; ++j) {
      int q = (int)rintf(fv[j] / scale);  // RNE, matches np.round
      q = max(-128, min(127, q));
      p |= (unsigned)(q & 0xff) << (8 * j);
    }
    packed[i] = p;
  }
  const int tm = row >> 8, f = (row >> 4) & 15, fr = row & 15;
  const int kt = t >> 2, kg = t & 3;
  int8_t* dst =
      xq2 + ((((size_t)(tm * 64 + kt) * 16 + f) * 64) + fr + 16 * kg) * 16;
  *(int4*)dst =
      make_int4((int)packed[0], (int)packed[1], (int)packed[2], (int)packed[3]);
}

// ------- W int32 [K][N] -> Wt2 int8 fragment order, NO LDS (verbatim R18) -------
__global__ __launch_bounds__(256) void transpose_pack(
    const int* __restrict__ W32, int8_t* __restrict__ Wt2, int K, int N) {
  const int t = threadIdx.x;
  const int tn = blockIdx.x;  // 256-col panel
  const int kt = blockIdx.y;  // 64-k tile
  const int nq = t & 63;      // n-quad within panel
  const int kg = t >> 6;      // 16-k group
  const int n0 = tn * 256 + nq * 4;
  const int kb = kt * 64 + kg * 16;

  v4i r[16];
#pragma unroll
  for (int k = 0; k < 16; ++k)
    r[k] = *(const v4i*)(W32 + (size_t)(kb + k) * N + n0);

  int o[4][4];
#pragma unroll
  for (int i = 0; i < 4; ++i)
#pragma unroll
    for (int j = 0; j < 4; ++j)
      o[i][j] = (r[4 * j + 0][i] & 0xff) | ((r[4 * j + 1][i] & 0xff) << 8) |
                ((r[4 * j + 2][i] & 0xff) << 16) | (r[4 * j + 3][i] << 24);

  int8_t* base = Wt2 + (((size_t)(tn * 64 + kt) * 16 + (nq >> 2)) * 64 +
                        4 * (nq & 3) + 16 * kg) * 16;
#pragma unroll
  for (int i = 0; i < 4; ++i)
    *(v4i*)(base + i * 16) = *(v4i*)&o[i][0];
}

// ---- int8 GEMM: compute-one-tile-behind pipeline. MFMA(T-1) ungated while ----
// ---- ds_reads(T) + stage(T+1) fly underneath. 2-slot A LDS ring, 2-slot     ----
// ---- breg/areg banks. One barrier + counted vmcnt(4) per tile, never drain. ----
__global__ __launch_bounds__(512, 2) void gemm_i8(
    const int8_t* __restrict__ Xq2, const int8_t* __restrict__ Wt2,
    const float* __restrict__ xs, const float* __restrict__ wsc,
    const float* __restrict__ bias, float* __restrict__ C) {
  __shared__ __align__(16) int8_t lA[2][16384];  // 32 KB: [slot][f][lane][16B]

  const int t = threadIdx.x;
  const int lane = t & 63;
  const int w = t >> 6;
  const int wr = w >> 2;  // 0..1 (M half: 128 rows)
  const int wc = w & 3;   // 0..3 (N quarter: 64 cols)
  const int fr = lane & 15;
  const int kg = lane >> 4;

  // bijective XCD swizzle: 1024 blocks = 8 XCD x (16 M x 8 N) rectangles
  const int bid = blockIdx.x;
  const int xcd = bid & 7;
  const int q = bid >> 3;
  const int tm = q & 15;
  const int tn = xcd * 8 + (q >> 4);
  const size_t rowA0 = (size_t)tm * BM;
  const size_t rowB0 = (size_t)tn * BN;

  // A tile (16 KB linear, fragment order); wave w stages 1KB chunks 2w, 2w+1.
  const int8_t* aqB = Xq2 + (size_t)tm * 1048576 + w * 2048 + (size_t)lane * 16;
  const int dstO = w * 2048;

#define STAGE(KT, SLOT)                                           \
  {                                                               \
    const int8_t* p = aqB + (size_t)(KT)*16384;                   \
    gload16(p, &lA[(SLOT)][0] + dstO);                            \
    gload16(p + 1024, &lA[(SLOT)][0] + dstO + 1024);              \
  }

  // B fragment base for this wave: f = wc*4 + nj
  const int8_t* bq = Wt2 + (size_t)tn * 1048576 + wc * 4096 + (size_t)lane * 16;

  v4i acc[8][4] = {};
  v4i areg[2][8], breg[2][4];  // banks by tile parity

#define LD(dst, ptr)                                        \
  asm volatile("global_load_dwordx4 %0, %1, off"            \
               : "=v"(dst)                                  \
               : "v"(ptr)                                   \
               : "memory")

#define LOADB(KT, S)                                        \
  {                                                         \
    const int8_t* bp = bq + (size_t)(KT)*16384;             \
    LD(breg[S][0], bp);                                     \
    LD(breg[S][1], bp + 1024);                              \
    LD(breg[S][2], bp + 2048);                              \
    LD(breg[S][3], bp + 3072);                              \
  }

  // 8 ds_reads of tile in slot P into areg bank P (lane-linear, conflict-free)
#define RD_A8(P)                                                            \
  _Pragma("unroll") for (int mi = 0; mi < 8; ++mi) areg[P][mi] =            \
      *(const v4i*)&lA[(P)][(wr * 8 + mi) * 1024 + lane * 16];

  // 32 ungated MFMAs of the PREVIOUS tile (bank PB) — operands long since ready
#define MFMA_ALL(PB)                                                        \
  __builtin_amdgcn_s_setprio(1);                                            \
  _Pragma("unroll") for (int mi = 0; mi < 8; ++mi)                          \
      _Pragma("unroll") for (int nj = 0; nj < 4; ++nj)                      \
          acc[mi][nj] = __builtin_amdgcn_mfma_i32_16x16x64_i8(              \
              areg[PB][mi], breg[PB][nj], acc[mi][nj], 0, 0, 0);            \
  __builtin_amdgcn_s_setprio(0);

#define SB __builtin_amdgcn_sched_barrier(0)

  // BODY(T): P = T&1.  Reads tile T (slot P -> bank P); computes tile T-1.
#define BODY(T, P)                                                            \
  {                                                                           \
    /* gate: my stage(T) landed (4 newest = B(T) may fly); barrier lifts */   \
    /* CU-wide: tile T resident in slot P; slot P^1 read-free (lgkm(0) of */  \
    /* body T-1 preceded its barrier arrival) */                              \
    asm volatile("s_waitcnt vmcnt(4)" ::: "memory");                          \
    __builtin_amdgcn_s_barrier();                                             \
    STAGE(((T) + 1) & (NT - 1), ((P) ^ 1));                                   \
    SB;                                                                       \
    RD_A8(P);                                                                 \
    SB;                                                                       \
    MFMA_ALL((P) ^ 1); /* tile T-1: no wait — loaded+drained last body */     \
    asm volatile("s_waitcnt lgkmcnt(0)" ::: "memory"); /* bank P complete */  \
    SB;                                                                       \
    LOADB(((T) + 1) & (NT - 1), ((P) ^ 1)); /* breg slot just consumed */     \
    SB;                                                                       \
  }

  // prologue: stage tiles 0,1; B tiles 0,1; drain once; preload tile 0 regs
  STAGE(0, 0);
  STAGE(1, 1);
  LOADB(0, 0);
  LOADB(1, 1);
  asm volatile("s_waitcnt vmcnt(0)" ::: "memory");
  __builtin_amdgcn_s_barrier();
  RD_A8(0);
  asm volatile("s_waitcnt lgkmcnt(0)" ::: "memory");
  SB;

  // bodies T=1..63 (computes tiles 0..62); epilogue computes tile 63
  BODY(1, 1);
  for (int kt = 2; kt < NT; kt += 2) {
    BODY(kt, 0);
    BODY(kt + 1, 1);
  }
  asm volatile("s_waitcnt vmcnt(0) lgkmcnt(0)" ::: "memory");
  SB;
  MFMA_ALL(1);  // tile 63 (bank 1, breg[1] = B(63), loaded at body 62)

  // epilogue: dequant + bias -> bf16-round -> f32 store
  // 16x16 C/D: col = lane&15, row = (lane>>4)*4 + reg
#pragma unroll
  for (int nj = 0; nj < 4; ++nj) {
    const int col_l = wc * 64 + nj * 16 + fr;
    const float wsv = wsc[rowB0 + col_l];
    const float bv = bias[rowB0 + col_l];
#pragma unroll
    for (int mi = 0; mi < 8; ++mi) {
#pragma unroll
      for (int r = 0; r < 4; ++r) {
        const size_t row = rowA0 + wr * 128 + mi * 16 + kg * 4 + r;
        const float f = (float)acc[mi][nj][r] * xs[row] * wsv + bv;
        C[row * GN + rowB0 + col_l] = __bfloat162float(__float2bfloat16(f));
      }
    }
  }
}

extern "C" void kernel_launch(void* const* d_in, const int* in_sizes, int n_in,
                              void* d_out, int out_size, void* d_ws, size_t ws_size,
                              hipStream_t stream) {
  const int M = GM, K = GK, N = GN;
  const float* x = (const float*)d_in[0];
  const int* W32 = (const int*)d_in[1];  // harness pushes integer inputs as int32
  const float* wsc = (const float*)d_in[2];
  const float* bias = (const float*)d_in[3];
  float* out = (float*)d_out;  // reference output dtype is float32 (bf16-rounded)

  // workspace layout: xs (16KB) | Xq2 (16MB packed) | Wt2 (64MB packed)
  float* xs = (float*)d_ws;
  int8_t* Xq2 = (int8_t*)d_ws + 16384;
  int8_t* Wt2 = (int8_t*)d_ws + 16384 + (size_t)M * K;

  transpose_pack<<<dim3(N / 256, K / 64), 256, 0, stream>>>(W32, Wt2, K, N);
  quant_rows<<<M, 256, 0, stream>>>(x, Xq2, xs, K);
  gemm_i8<<<dim3((M / BM) * (N / BN)), 512, 0, stream>>>(Xq2, Wt2, xs, wsc, bias,
                                                         out);
}